// Round 17
// baseline (198.829 us; speedup 1.0000x reference)
//
#include <hip/hip_runtime.h>
#include <hip/hip_bf16.h>
#include <math.h>

typedef __attribute__((ext_vector_type(8))) short short8;
typedef __attribute__((ext_vector_type(8))) unsigned short ushort8;
typedef __attribute__((ext_vector_type(4))) float f32x4;
typedef __attribute__((ext_vector_type(2))) float f32x2;

#define T_SEQ 4096
#define D_MODEL 2048
#define N_HEADS 16
#define N_KV 8
#define HEAD_DIM 128
#define QSCALE 0.08838834764831845f

__device__ __forceinline__ float bf2f(unsigned short u) {
  union { unsigned int i; float f; } x; x.i = ((unsigned int)u) << 16; return x.f;
}
__device__ __forceinline__ unsigned short f2bf(float f) {
  union { float f; unsigned int i; } x; x.f = f;
  unsigned int i = x.i;
  unsigned int r = i + 0x7fffu + ((i >> 16) & 1u);
  return (unsigned short)(r >> 16);
}

// ---------------- x (f32) -> bf16  +  RoPE sin/cos table (merged) ----------------
__global__ __launch_bounds__(256) void prep_kernel(const float* __restrict__ x,
                                                   unsigned short* __restrict__ xb,
                                                   const int* __restrict__ segpos,
                                                   float2* __restrict__ tab) {
  int b = blockIdx.x;
  if (b < 4096) {
    int idx = b * 256 + threadIdx.x;
    const float4* p = reinterpret_cast<const float4*>(x) + (size_t)idx * 2;
    float4 a = p[0], c = p[1];
    ushort8 o;
    o[0] = f2bf(a.x); o[1] = f2bf(a.y); o[2] = f2bf(a.z); o[3] = f2bf(a.w);
    o[4] = f2bf(c.x); o[5] = f2bf(c.y); o[6] = f2bf(c.z); o[7] = f2bf(c.w);
    reinterpret_cast<ushort8*>(xb)[idx] = o;
  } else {
    int idx = (b - 4096) * 256 + threadIdx.x;   // t*64 + i
    int t = idx >> 6, i = idx & 63;
    float pos = (float)segpos[t];
    float ts = powf(10000.f, (float)(2 * i) / 128.f);
    float ang = pos / ts;
    tab[idx] = make_float2(sinf(ang), cosf(ang));
  }
}

// ---------------- merged q_w + kv_w transpose: f32 [2048][128] -> bf16 [128][2048] ----------------
__global__ __launch_bounds__(256) void wqkv_transpose_kernel(const float* __restrict__ q_w,
                                                             const float* __restrict__ kv_w,
                                                             unsigned short* __restrict__ Wt) {
  __shared__ float tile[32][33];
  int z = blockIdx.z;   // 0..31: 16 q heads then 16 kv slots
  const float* src = (z < 16) ? q_w + (size_t)z * 2048 * 128
                              : kv_w + (size_t)(z - 16) * 2048 * 128;
  unsigned short* dst = Wt + (size_t)z * 128 * 2048;
  int c0 = blockIdx.x * 32, r0 = blockIdx.y * 32;
  int tx = threadIdx.x & 31, ty = threadIdx.x >> 5;
#pragma unroll
  for (int i = 0; i < 4; ++i)
    tile[ty + i * 8][tx] = src[(size_t)(r0 + ty + i * 8) * 128 + c0 + tx];
  __syncthreads();
#pragma unroll
  for (int i = 0; i < 4; ++i)
    dst[(size_t)(c0 + ty + i * 8) * 2048 + r0 + tx] = f2bf(tile[tx][ty + i * 8]);
}

#define G2L(gp, lp)                                                           \
  __builtin_amdgcn_global_load_lds(                                           \
      (const __attribute__((address_space(1))) void*)(gp),                    \
      (__attribute__((address_space(3))) void*)(lp), 16, 0, 0)
#define GBAR() asm volatile("s_barrier" ::: "memory")
#define VMW(n) asm volatile("s_waitcnt vmcnt(" #n ")" ::: "memory")
#define LG0()  asm volatile("s_waitcnt lgkmcnt(0)" ::: "memory")

// ================= 256x256 8-phase GEMM (QKV): C = A[M][K] * Bt[N][K]^T =================
// (unchanged from round 15 — best-known QKV config)
template <int OUT_BF16>
__global__ __launch_bounds__(512, 2) void gemm256_kernel(const unsigned short* __restrict__ A,
                                                         const unsigned short* __restrict__ Bt,
                                                         void* __restrict__ Cout,
                                                         int M, int N, int K) {
  extern __shared__ unsigned short smem[];
  unsigned short* ldsA = smem;                      // [2 buf][2 half][8192]
  unsigned short* ldsB = smem + 32768;              // [2 buf][2 half][8192]
  const int tid = threadIdx.x;
  const int lane = tid & 63, wave = tid >> 6;
  const int wm = wave >> 2, wn = wave & 3;
  const int lr = lane & 15, lg = lane >> 4;
  const int swz = (lr & 7) << 3;
  const int c0s = (lg * 8) ^ swz;
  const int c1s = (32 + lg * 8) ^ swz;

  int id = blockIdx.y * gridDim.x + blockIdx.x;
  int nb = gridDim.x * gridDim.y;
  int sw = (id & 7) * (nb >> 3) + (id >> 3);        // bijective, nb % 8 == 0
  const long brow = (long)(sw / gridDim.x) * 256;
  const long bcol = (long)(sw % gridDim.x) * 256;

  const unsigned short* Ag = A + brow * K;
  const unsigned short* Bg = Bt + bcol * K;

  const int r0 = tid >> 3;
  const int cs = ((tid & 7) * 8) ^ ((r0 & 7) << 3);

#define ST_A(tt, b, a)                                                        \
  { G2L(Ag + (size_t)((a) * 128 + r0) * K + (size_t)(tt) * 64 + cs,           \
        ldsA + (b) * 16384 + (a) * 8192 + tid * 8);                           \
    G2L(Ag + (size_t)((a) * 128 + r0 + 64) * K + (size_t)(tt) * 64 + cs,      \
        ldsA + (b) * 16384 + (a) * 8192 + 4096 + tid * 8); }
#define ST_B(tt, b, h)                                                        \
  { G2L(Bg + (size_t)((h) * 128 + r0) * K + (size_t)(tt) * 64 + cs,           \
        ldsB + (b) * 16384 + (h) * 8192 + tid * 8);                           \
    G2L(Bg + (size_t)((h) * 128 + r0 + 64) * K + (size_t)(tt) * 64 + cs,      \
        ldsB + (b) * 16384 + (h) * 8192 + 4096 + tid * 8); }

  f32x4 acc[8][4] = {};
  short8 bf[4][2];
  short8 af[4];

#define RD_B(b)                                                               \
  { const unsigned short* pb = ldsB + (b) * 16384 + wn * 4096;                \
    _Pragma("unroll")                                                         \
    for (int n = 0; n < 4; ++n) {                                             \
      bf[n][0] = *(const short8*)(pb + (n * 16 + lr) * 64 + c0s);             \
      bf[n][1] = *(const short8*)(pb + (n * 16 + lr) * 64 + c1s);             \
    } }
#define RD_A(b, mb)                                                           \
  { const unsigned short* pa = ldsA + (b) * 16384 + wm * 8192;                \
    af[0] = *(const short8*)(pa + ((mb) * 16 + lr) * 64 + c0s);               \
    af[1] = *(const short8*)(pa + ((mb) * 16 + lr) * 64 + c1s);               \
    af[2] = *(const short8*)(pa + ((mb) * 16 + 16 + lr) * 64 + c0s);          \
    af[3] = *(const short8*)(pa + ((mb) * 16 + 16 + lr) * 64 + c1s); }
#define MFMA2(mb)                                                             \
  { __builtin_amdgcn_s_setprio(1);                                            \
    _Pragma("unroll")                                                         \
    for (int n = 0; n < 4; ++n) {                                             \
      acc[mb][n]     = __builtin_amdgcn_mfma_f32_16x16x32_bf16(af[0], bf[n][0], acc[mb][n], 0, 0, 0);     \
      acc[mb][n]     = __builtin_amdgcn_mfma_f32_16x16x32_bf16(af[1], bf[n][1], acc[mb][n], 0, 0, 0);     \
      acc[mb + 1][n] = __builtin_amdgcn_mfma_f32_16x16x32_bf16(af[2], bf[n][0], acc[mb + 1][n], 0, 0, 0); \
      acc[mb + 1][n] = __builtin_amdgcn_mfma_f32_16x16x32_bf16(af[3], bf[n][1], acc[mb + 1][n], 0, 0, 0); \
    }                                                                         \
    __builtin_amdgcn_s_setprio(0); }

  const int NT = K >> 6;
  ST_B(0, 0, 0); ST_B(0, 0, 1); ST_A(0, 0, 0); ST_A(0, 0, 1);
  ST_B(1, 1, 0); ST_B(1, 1, 1);
  VMW(4); GBAR();
  for (int j = 0; j < (NT >> 1); ++j) {
    const int c1 = 2 * j + 1, t2 = 2 * j + 2, t3 = 2 * j + 3;
    const bool s2 = t2 < NT, s3 = t3 < NT;
    RD_B(0); RD_A(0, 0); ST_A(c1, 1, 0);
    GBAR(); LG0(); MFMA2(0); GBAR();
    RD_A(0, 2); ST_A(c1, 1, 1);
    if (s2) ST_B(t2, 0, 0);
    GBAR(); MFMA2(2); GBAR();
    RD_A(0, 4);
    if (s2) ST_B(t2, 0, 1);
    GBAR(); MFMA2(4); GBAR();
    RD_A(0, 6);
    if (s2) { VMW(4); } else { VMW(0); }
    GBAR(); LG0(); MFMA2(6); GBAR();
    RD_B(1); RD_A(1, 0);
    if (s2) ST_A(t2, 0, 0);
    GBAR(); LG0(); MFMA2(0); GBAR();
    RD_A(1, 2);
    if (s2) ST_A(t2, 0, 1);
    if (s3) ST_B(t3, 1, 0);
    GBAR(); MFMA2(2); GBAR();
    RD_A(1, 4);
    if (s3) ST_B(t3, 1, 1);
    GBAR(); MFMA2(4); GBAR();
    RD_A(1, 6);
    if (s3) { VMW(4); } else { VMW(0); }
    GBAR(); LG0(); MFMA2(6); GBAR();
  }

#pragma unroll
  for (int m = 0; m < 8; ++m) {
#pragma unroll
    for (int i = 0; i < 4; ++i) {
      long row = brow + wm * 128 + m * 16 + lg * 4 + i;
#pragma unroll
      for (int n = 0; n < 4; ++n) {
        long col = bcol + wn * 64 + n * 16 + lr;
        if (OUT_BF16)
          ((unsigned short*)Cout)[row * N + col] = f2bf(acc[m][n][i]);
        else
          ((float*)Cout)[row * N + col] = acc[m][n][i];
      }
    }
  }
#undef ST_A
#undef ST_B
#undef RD_A
#undef RD_B
#undef MFMA2
}

// ================= 128x256 O-proj GEMM, 3-deep pipeline, ONE fat phase per K-tile ==========
// Diagnosis: per-phase cost is ~fixed (barrier convoy), so halve phases: all 16 ds_reads +
// all 6 staging G2L + counted VMW(6) before ONE barrier-pair, then 32 MFMA straight.
// Safety: buf (t+2)%3's last reads (iter t-1) drained at t-1's post-barrier LG0, >=1
// closing barrier before this iter's overwrite. VMW(6) drains tile t+1 (issued 1 iter
// earlier); tile t's data was drained by iter t-1's VMW. Never 0 mid-loop.
__global__ __launch_bounds__(512, 1) void gemm_op3_kernel(const unsigned short* __restrict__ A,
                                                          const unsigned short* __restrict__ Bt,
                                                          float* __restrict__ Cout,
                                                          int M, int N, int K) {
  extern __shared__ unsigned short smem[];
  unsigned short* ldsA = smem;                      // [3 buf][8192]      48 KB
  unsigned short* ldsB = smem + 3 * 8192;           // [3 buf][2][8192]   96 KB
  const int tid = threadIdx.x;
  const int lane = tid & 63, wave = tid >> 6;
  const int wm = wave >> 2, wn = wave & 3;
  const int lr = lane & 15, lg = lane >> 4;
  const int swz = (lr & 7) << 3;
  const int c0s = (lg * 8) ^ swz;
  const int c1s = (32 + lg * 8) ^ swz;

  int id = blockIdx.y * gridDim.x + blockIdx.x;
  int sw = (id & 7) * 32 + (id >> 3);
  int c = sw >> 5, l = sw & 31;
  const long brow = (long)((c >> 2) * 16 + (l & 15)) * 128;
  const long bcol = (long)((c & 3) * 2 + (l >> 4)) * 256;

  const unsigned short* Ag = A + brow * K;
  const unsigned short* Bg = Bt + bcol * K;

  const int r0 = tid >> 3;
  const int cs = ((tid & 7) * 8) ^ ((r0 & 7) << 3);

#define ST_A3(tt, b)                                                          \
  { G2L(Ag + (size_t)(r0) * K + (size_t)(tt) * 64 + cs,                       \
        ldsA + (b) * 8192 + tid * 8);                                         \
    G2L(Ag + (size_t)(r0 + 64) * K + (size_t)(tt) * 64 + cs,                  \
        ldsA + (b) * 8192 + 4096 + tid * 8); }
#define ST_B3(tt, b, h)                                                       \
  { G2L(Bg + (size_t)((h) * 128 + r0) * K + (size_t)(tt) * 64 + cs,           \
        ldsB + (b) * 16384 + (h) * 8192 + tid * 8);                           \
    G2L(Bg + (size_t)((h) * 128 + r0 + 64) * K + (size_t)(tt) * 64 + cs,      \
        ldsB + (b) * 16384 + (h) * 8192 + 4096 + tid * 8); }

  f32x4 acc[4][4] = {};
  short8 bf[4][2];
  short8 af0[4], af1[4];

#define RD_B3(b)                                                              \
  { const unsigned short* pb = ldsB + (b) * 16384 + wn * 4096;                \
    _Pragma("unroll")                                                         \
    for (int n = 0; n < 4; ++n) {                                             \
      bf[n][0] = *(const short8*)(pb + (n * 16 + lr) * 64 + c0s);             \
      bf[n][1] = *(const short8*)(pb + (n * 16 + lr) * 64 + c1s);             \
    } }
#define RD_A3(b, mb, dst)                                                     \
  { const unsigned short* pa = ldsA + (b) * 8192 + wm * 4096;                 \
    dst[0] = *(const short8*)(pa + ((mb) * 16 + lr) * 64 + c0s);              \
    dst[1] = *(const short8*)(pa + ((mb) * 16 + lr) * 64 + c1s);              \
    dst[2] = *(const short8*)(pa + ((mb) * 16 + 16 + lr) * 64 + c0s);         \
    dst[3] = *(const short8*)(pa + ((mb) * 16 + 16 + lr) * 64 + c1s); }
#define MFMA2X(mb, afx)                                                       \
  { _Pragma("unroll")                                                         \
    for (int n = 0; n < 4; ++n) {                                             \
      acc[mb][n]     = __builtin_amdgcn_mfma_f32_16x16x32_bf16(afx[0], bf[n][0], acc[mb][n], 0, 0, 0);     \
      acc[mb][n]     = __builtin_amdgcn_mfma_f32_16x16x32_bf16(afx[1], bf[n][1], acc[mb][n], 0, 0, 0);     \
      acc[mb + 1][n] = __builtin_amdgcn_mfma_f32_16x16x32_bf16(afx[2], bf[n][0], acc[mb + 1][n], 0, 0, 0); \
      acc[mb + 1][n] = __builtin_amdgcn_mfma_f32_16x16x32_bf16(afx[3], bf[n][1], acc[mb + 1][n], 0, 0, 0); \
    } }

  const int NT = K >> 6;
  ST_B3(0, 0, 0); ST_B3(0, 0, 1); ST_A3(0, 0);
  ST_B3(1, 1, 0); ST_B3(1, 1, 1); ST_A3(1, 1);
  VMW(6); GBAR();                               // tile0 landed; tile1 (6) in flight
  int b = 0;
  for (int t = 0; t < NT; ++t) {
    int bn = b + 2; if (bn >= 3) bn -= 3;
    const bool st = (t + 2) < NT;
    // one fat phase: all reads of buf b, all staging of tile t+2 into buf bn
    RD_B3(b); RD_A3(b, 0, af0); RD_A3(b, 2, af1);
    if (st) { ST_B3(t + 2, bn, 0); ST_B3(t + 2, bn, 1); ST_A3(t + 2, bn); VMW(6); }
    else    { VMW(0); }
    GBAR(); LG0();
    __builtin_amdgcn_s_setprio(1);
    MFMA2X(0, af0); MFMA2X(2, af1);
    __builtin_amdgcn_s_setprio(0);
    GBAR();
    b = b + 1; if (b >= 3) b = 0;
  }

#pragma unroll
  for (int m = 0; m < 4; ++m) {
#pragma unroll
    for (int i = 0; i < 4; ++i) {
      long row = brow + wm * 64 + m * 16 + lg * 4 + i;
#pragma unroll
      for (int n = 0; n < 4; ++n) {
        long col = bcol + wn * 64 + n * 16 + lr;
        Cout[row * N + col] = acc[m][n][i];
      }
    }
  }
#undef ST_A3
#undef ST_B3
#undef RD_A3
#undef RD_B3
#undef MFMA2X
}

// ---------------- merged RoPE apply + V transpose + o_w transpose ----------------
__global__ __launch_bounds__(256) void rope_vt_ow_kernel(const unsigned short* __restrict__ raw,
                                                         const float2* __restrict__ tab,
                                                         unsigned short* __restrict__ Qb,
                                                         unsigned short* __restrict__ Kb,
                                                         unsigned short* __restrict__ Vt,
                                                         const float* __restrict__ o_w,
                                                         unsigned short* __restrict__ o_wt) {
  __shared__ unsigned short tileU[32][33];
  __shared__ float tileF[32][33];
  int b = blockIdx.x;
  if (b < 3072) {
    int gid = b * 256 + threadIdx.x;
    int j = gid & 7;
    int rem = gid >> 3;
    int hs = rem % 24;
    int t = rem / 24;
    int i0 = j * 8;
    float sv[8], cv[8];
    const float2* tp = tab + t * 64 + i0;
#pragma unroll
    for (int q = 0; q < 8; ++q) { float2 sc2 = tp[q]; sv[q] = sc2.x; cv[q] = sc2.y; }
    if (hs < 16) {
      const unsigned short* p = raw + (size_t)t * 4096 + hs * 128 + i0;
      ushort8 a = *(const ushort8*)p;
      ushort8 c = *(const ushort8*)(p + 64);
      ushort8 o1, o2;
#pragma unroll
      for (int q = 0; q < 8; ++q) {
        float fa = bf2f(a[q]), fb = bf2f(c[q]);
        o1[q] = f2bf((fa * cv[q] - fb * sv[q]) * QSCALE);
        o2[q] = f2bf((fb * cv[q] + fa * sv[q]) * QSCALE);
      }
      unsigned short* qp = Qb + ((size_t)hs * T_SEQ + t) * 128 + i0;
      *(ushort8*)qp = o1;
      *(ushort8*)(qp + 64) = o2;
    } else {
      int kn = hs - 16;
      const unsigned short* p = raw + (size_t)t * 4096 + 2048 + kn * 128 + i0;
      ushort8 a = *(const ushort8*)p;
      ushort8 c = *(const ushort8*)(p + 64);
      ushort8 o1, o2;
#pragma unroll
      for (int q = 0; q < 8; ++q) {
        float fa = bf2f(a[q]), fb = bf2f(c[q]);
        o1[q] = f2bf(fa * cv[q] - fb * sv[q]);
        o2[q] = f2bf(fb * cv[q] + fa * sv[q]);
      }
      unsigned short* kp = Kb + ((size_t)kn * T_SEQ + t) * 128 + i0;
      *(ushort8*)kp = o1;
      *(ushort8*)(kp + 64) = o2;
    }
  } else if (b < 7168) {
    int id = b - 3072;                 // 0..4095: V transpose
    int bx = id & 3, by = (id >> 2) & 127, bz = id >> 9;
    const unsigned short* src = raw + 3072 + (size_t)bz * 128;
    unsigned short* dst = Vt + (size_t)bz * 128 * 4096;
    int c0 = bx * 32, r0 = by * 32;
    int tx = threadIdx.x & 31, ty = threadIdx.x >> 5;
#pragma unroll
    for (int i = 0; i < 4; ++i)
      tileU[ty + i * 8][tx] = src[(size_t)(r0 + ty + i * 8) * 4096 + c0 + tx];
    __syncthreads();
#pragma unroll
    for (int i = 0; i < 4; ++i)
      dst[(size_t)(c0 + ty + i * 8) * 4096 + r0 + tx] = tileU[tx][ty + i * 8];
  } else {
    int id = b - 7168;                 // 0..4095: o_w transpose f32 -> bf16^T
    int bx = id & 63, by = id >> 6;
    int c0 = bx * 32, r0 = by * 32;
    int tx = threadIdx.x & 31, ty = threadIdx.x >> 5;
#pragma unroll
    for (int i = 0; i < 4; ++i)
      tileF[ty + i * 8][tx] = o_w[(size_t)(r0 + ty + i * 8) * 2048 + c0 + tx];
    __syncthreads();
#pragma unroll
    for (int i = 0; i < 4; ++i)
      o_wt[(size_t)(c0 + ty + i * 8) * 2048 + r0 + tx] = f2bf(tileF[tx][ty + i * 8]);
  }
}

// ---------------- Flash attention: sliding window + tanh soft-cap ----------------
__global__ __launch_bounds__(512, 2) void attn_kernel(const unsigned short* __restrict__ Qb,
                                                      const unsigned short* __restrict__ Kb,
                                                      const unsigned short* __restrict__ Vt,
                                                      unsigned short* __restrict__ enc) {
  __shared__ unsigned short Ks[2][64][128];  // [buf][key][d], global col pre-swizzled
  __shared__ unsigned short Vs[2][128][64];  // [buf][d][key]
  __shared__ unsigned short Ps[8][32][72];   // [wave][q][key]
  int rawb = blockIdx.x;                     // 256 blocks
  int lin = (rawb & 7) * 32 + (rawb >> 3);   // bijective; 32/XCD = 2 heads = 1 kv head
  const int h = lin >> 4;
  const int qb0 = (lin & 15) * 256;
  const int kvh = h >> 1;
  const int tid = threadIdx.x, lane = tid & 63, wave = tid >> 6;
  const int qw = qb0 + wave * 32;
  const int lr = lane & 15, lg = lane >> 4;
  const int sw = (lr & 7) << 3;
  const int ck0 = (lg * 8) ^ sw, ck1 = (32 + lg * 8) ^ sw;
  const int ck2 = (64 + lg * 8) ^ sw, ck3 = (96 + lg * 8) ^ sw;

  short8 aq[2][4];
#pragma unroll
  for (int g = 0; g < 2; ++g) {
    const unsigned short* qp = Qb + ((size_t)h * T_SEQ + qw + g * 16 + lr) * 128 + lg * 8;
#pragma unroll
    for (int c = 0; c < 4; ++c) aq[g][c] = *(const short8*)(qp + c * 32);
  }
  f32x4 acc[2][8] = {};
  float lsum[2] = {0.f, 0.f};

  const int s_lo = (qb0 - 1023) > 0 ? (qb0 - 1023) : 0;
  const int kb_lo = s_lo >> 6, kb_hi = (qb0 + 255) >> 6;

  const int rK = tid >> 4;                 // 0..31: K rows rK, rK+32
  const int cpK = (tid & 15) * 8;
  const int colK = cpK ^ ((rK & 7) << 3);
  const int rV = tid >> 3;                 // 0..63: V rows rV, rV+64
  const int cpV = (tid & 7) * 8;
  const int colV = cpV ^ ((rV & 7) << 3);
  const unsigned short* kgb = Kb + ((size_t)kvh * T_SEQ + rK) * 128 + colK;
  const unsigned short* vgb = Vt + ((size_t)kvh * 128 + rV) * T_SEQ + colV;

  ushort8 kr0, kr1, vr0, vr1;
  {
    const int s0g = kb_lo * 64;
    kr0 = *(const ushort8*)(kgb + (size_t)s0g * 128);
    kr1 = *(const ushort8*)(kgb + (size_t)(s0g + 32) * 128);
    vr0 = *(const ushort8*)(vgb + s0g);
    vr1 = *(const ushort8*)(vgb + (size_t)64 * T_SEQ + s0g);
  }

  const int qg0 = qw + lr, qg1 = qw + 16 + lr;
  for (int kb = kb_lo; kb <= kb_hi; ++kb) {
    const int s0g = kb * 64;
    const int buf = kb & 1;
    *(ushort8*)&Ks[buf][rK][cpK] = kr0;
    *(ushort8*)&Ks[buf][rK + 32][cpK] = kr1;
    *(ushort8*)&Vs[buf][rV][cpV] = vr0;
    *(ushort8*)&Vs[buf][rV + 64][cpV] = vr1;
    __syncthreads();
    if (kb < kb_hi) {
      const int sn = s0g + 64;
      kr0 = *(const ushort8*)(kgb + (size_t)sn * 128);
      kr1 = *(const ushort8*)(kgb + (size_t)(sn + 32) * 128);
      vr0 = *(const ushort8*)(vgb + sn);
      vr1 = *(const ushort8*)(vgb + (size_t)64 * T_SEQ + sn);
    }
    if (s0g > qw + 31 || s0g + 63 < qw - 1023) continue;
    const bool interior = (s0g + 63 <= qw) && (s0g >= qw - 992);

    f32x4 sT0[4] = {}, sT1[4] = {};
    __builtin_amdgcn_s_setprio(1);
#pragma unroll
    for (int st = 0; st < 4; ++st) {
      const unsigned short* kp = &Ks[buf][st * 16 + lr][0];
      short8 k0 = *(const short8*)(kp + ck0);
      short8 k1 = *(const short8*)(kp + ck1);
      short8 k2 = *(const short8*)(kp + ck2);
      short8 k3 = *(const short8*)(kp + ck3);
      sT0[st] = __builtin_amdgcn_mfma_f32_16x16x32_bf16(k0, aq[0][0], sT0[st], 0, 0, 0);
      sT1[st] = __builtin_amdgcn_mfma_f32_16x16x32_bf16(k0, aq[1][0], sT1[st], 0, 0, 0);
      sT0[st] = __builtin_amdgcn_mfma_f32_16x16x32_bf16(k1, aq[0][1], sT0[st], 0, 0, 0);
      sT1[st] = __builtin_amdgcn_mfma_f32_16x16x32_bf16(k1, aq[1][1], sT1[st], 0, 0, 0);
      sT0[st] = __builtin_amdgcn_mfma_f32_16x16x32_bf16(k2, aq[0][2], sT0[st], 0, 0, 0);
      sT1[st] = __builtin_amdgcn_mfma_f32_16x16x32_bf16(k2, aq[1][2], sT1[st], 0, 0, 0);
      sT0[st] = __builtin_amdgcn_mfma_f32_16x16x32_bf16(k3, aq[0][3], sT0[st], 0, 0, 0);
      sT1[st] = __builtin_amdgcn_mfma_f32_16x16x32_bf16(k3, aq[1][3], sT1[st], 0, 0, 0);
    }
    __builtin_amdgcn_s_setprio(0);

#pragma unroll
    for (int g = 0; g < 2; ++g) {
      const f32x4* sTg = g ? sT1 : sT0;
      const int qgg = g ? qg1 : qg0;
#pragma unroll
      for (int st = 0; st < 4; ++st) {
        f32x4 svv = sTg[st];
        f32x2 sa, sb;
        sa[0] = svv[0]; sa[1] = svv[1]; sb[0] = svv[2]; sb[1] = svv[3];
        f32x2 ua = sa * sa, ub = sb * sb;
        f32x2 numa = ua * 4.0e-4f + 15.f, numb = ub * 4.0e-4f + 15.f;
        f32x2 dena = ua * 2.4e-3f + 15.f, denb = ub * 2.4e-3f + 15.f;
        f32x2 ra, rb;
        ra[0] = __builtin_amdgcn_rcpf(dena[0]); ra[1] = __builtin_amdgcn_rcpf(dena[1]);
        rb[0] = __builtin_amdgcn_rcpf(denb[0]); rb[1] = __builtin_amdgcn_rcpf(denb[1]);
        f32x2 ea = (sa * 1.44269504f) * numa * ra;
        f32x2 eb = (sb * 1.44269504f) * numb * rb;
        float e[4] = {ea[0], ea[1], eb[0], eb[1]};
        float p[4];
#pragma unroll
        for (int r = 0; r < 4; ++r) {
          if (!interior) {
            int sg = s0g + st * 16 + lg * 4 + r;
            e[r] = ((unsigned)(qgg - sg) <= 1023u) ? e[r] : -__builtin_inff();
          }
          asm("v_exp_f32 %0, %1" : "=v"(p[r]) : "v"(e[r]));
        }
        lsum[g] += (p[0] + p[1]) + (p[2] + p[3]);
        unsigned u0, u1;
        asm("v_cvt_pk_bf16_f32 %0, %1, %2" : "=v"(u0) : "v"(p[0]), "v"(p[1]));
        asm("v_cvt_pk_bf16_f32 %0, %1, %2" : "=v"(u1) : "v"(p[2]), "v"(p[3]));
        uint2 w; w.x = u0; w.y = u1;
        *(uint2*)&Ps[wave][g * 16 + lr][st * 16 + lg * 4] = w;
      }
    }
    short8 pa00 = *(const short8*)&Ps[wave][lr][lg * 8];
    short8 pa01 = *(const short8*)&Ps[wave][lr][32 + lg * 8];
    short8 pa10 = *(const short8*)&Ps[wave][16 + lr][lg * 8];
    short8 pa11 = *(const short8*)&Ps[wave][16 + lr][32 + lg * 8];
    __builtin_amdgcn_s_setprio(1);
#pragma unroll
    for (int d0 = 0; d0 < 8; ++d0) {
      const unsigned short* vp = &Vs[buf][d0 * 16 + lr][0];
      short8 bv0 = *(const short8*)(vp + ((lg * 8) ^ sw));
      short8 bv1 = *(const short8*)(vp + ((32 + lg * 8) ^ sw));
      acc[0][d0] = __builtin_amdgcn_mfma_f32_16x16x32_bf16(pa00, bv0, acc[0][d0], 0, 0, 0);
      acc[1][d0] = __builtin_amdgcn_mfma_f32_16x16x32_bf16(pa10, bv0, acc[1][d0], 0, 0, 0);
      acc[0][d0] = __builtin_amdgcn_mfma_f32_16x16x32_bf16(pa01, bv1, acc[0][d0], 0, 0, 0);
      acc[1][d0] = __builtin_amdgcn_mfma_f32_16x16x32_bf16(pa11, bv1, acc[1][d0], 0, 0, 0);
    }
    __builtin_amdgcn_s_setprio(0);
  }

#pragma unroll
  for (int g = 0; g < 2; ++g) {
    float l = lsum[g];
    l += __shfl_xor(l, 16);
    l += __shfl_xor(l, 32);
#pragma unroll
    for (int r = 0; r < 4; ++r) {
      float lt = __shfl(l, lg * 4 + r);
      float inv = __builtin_amdgcn_rcpf(lt);
      int row = qw + g * 16 + lg * 4 + r;
      unsigned short* op = enc + (size_t)row * D_MODEL + h * 128 + lr;
#pragma unroll
      for (int d0 = 0; d0 < 8; ++d0) op[d0 * 16] = f2bf(acc[g][d0][r] * inv);
    }
  }
}

// ---------------- launch ----------------
extern "C" void kernel_launch(void* const* d_in, const int* in_sizes, int n_in,
                              void* d_out, int out_size, void* d_ws, size_t ws_size,
                              hipStream_t stream) {
  const float* x = (const float*)d_in[0];
  const int* segpos = (const int*)d_in[1];
  // d_in[2]: attn_mask (pure causal tril) — computed analytically, not read
  const float* q_w = (const float*)d_in[3];
  const float* kv_w = (const float*)d_in[4];
  const float* o_w = (const float*)d_in[5];
  float* out = (float*)d_out;
  char* ws = (char*)d_ws;

  const size_t OFF_XB = 0;                       // 16.8 MB  x bf16 [4096][2048]
  const size_t OFF_WT = OFF_XB + 16777216;       // 16.8 MB  Wqkv^T bf16 [4096][2048]
  const size_t OFF_RAW = OFF_WT + 16777216;      // 33.6 MB  qkv raw bf16 [4096][4096]
  const size_t OFF_KB = OFF_RAW + 33554432;      // 8.4 MB   K roped [8][4096][128]
  const size_t OFF_VT = OFF_KB + 8388608;        // 8.4 MB   V^T [8][128][4096]
  const size_t OFF_TAB = OFF_VT + 8388608;       // 2 MB     rope table
  unsigned short* xb = (unsigned short*)(ws + OFF_XB);
  unsigned short* Wt = (unsigned short*)(ws + OFF_WT);
  unsigned short* raw = (unsigned short*)(ws + OFF_RAW);
  unsigned short* Kb = (unsigned short*)(ws + OFF_KB);
  unsigned short* Vt = (unsigned short*)(ws + OFF_VT);
  float2* tab = (float2*)(ws + OFF_TAB);
  unsigned short* o_wt = xb;   // alias: built after qkv GEMM consumed xb
  unsigned short* Qb = Wt;     // alias: built after qkv GEMM consumed Wt
  unsigned short* enc = raw;   // alias: written after V transpose consumed raw

  hipFuncSetAttribute((const void*)(gemm256_kernel<1>),
                      hipFuncAttributeMaxDynamicSharedMemorySize, 131072);
  hipFuncSetAttribute((const void*)gemm_op3_kernel,
                      hipFuncAttributeMaxDynamicSharedMemorySize, 147456);

  prep_kernel<<<dim3(5120), dim3(256), 0, stream>>>(x, xb, segpos, tab);
  wqkv_transpose_kernel<<<dim3(4, 64, 32), dim3(256), 0, stream>>>(q_w, kv_w, Wt);
  // qkv projection: 256x256 tile, 256 blocks
  gemm256_kernel<1><<<dim3(16, 16), dim3(512), 131072, stream>>>(xb, Wt, (void*)raw, 4096, 4096, 2048);
  // rope (3072) + V transpose (4096) + o_w transpose (4096)
  rope_vt_ow_kernel<<<dim3(11264), dim3(256), 0, stream>>>(raw, tab, Qb, Kb, Vt, o_w, o_wt);
  attn_kernel<<<dim3(256), dim3(512), 0, stream>>>(Qb, Kb, Vt, enc);
  // output projection: 128x256 tile, 3-deep pipeline, one fat phase per K-tile, 256 blocks
  gemm_op3_kernel<<<dim3(8, 32), dim3(512), 147456, stream>>>(enc, o_wt, out, 4096, 2048, 2048);
}

// Round 18
// 197.458 us; speedup vs baseline: 1.0069x; 1.0069x over previous
//
#include <hip/hip_runtime.h>
#include <hip/hip_bf16.h>
#include <math.h>

typedef __attribute__((ext_vector_type(8))) short short8;
typedef __attribute__((ext_vector_type(8))) unsigned short ushort8;
typedef __attribute__((ext_vector_type(4))) float f32x4;
typedef __attribute__((ext_vector_type(2))) float f32x2;

#define T_SEQ 4096
#define D_MODEL 2048
#define N_HEADS 16
#define N_KV 8
#define HEAD_DIM 128
#define QSCALE 0.08838834764831845f

__device__ __forceinline__ float bf2f(unsigned short u) {
  union { unsigned int i; float f; } x; x.i = ((unsigned int)u) << 16; return x.f;
}
__device__ __forceinline__ unsigned short f2bf(float f) {
  union { float f; unsigned int i; } x; x.f = f;
  unsigned int i = x.i;
  unsigned int r = i + 0x7fffu + ((i >> 16) & 1u);
  return (unsigned short)(r >> 16);
}

// ---------------- x (f32) -> bf16  +  RoPE sin/cos table (merged) ----------------
__global__ __launch_bounds__(256) void prep_kernel(const float* __restrict__ x,
                                                   unsigned short* __restrict__ xb,
                                                   const int* __restrict__ segpos,
                                                   float2* __restrict__ tab) {
  int b = blockIdx.x;
  if (b < 4096) {
    int idx = b * 256 + threadIdx.x;
    const float4* p = reinterpret_cast<const float4*>(x) + (size_t)idx * 2;
    float4 a = p[0], c = p[1];
    ushort8 o;
    o[0] = f2bf(a.x); o[1] = f2bf(a.y); o[2] = f2bf(a.z); o[3] = f2bf(a.w);
    o[4] = f2bf(c.x); o[5] = f2bf(c.y); o[6] = f2bf(c.z); o[7] = f2bf(c.w);
    reinterpret_cast<ushort8*>(xb)[idx] = o;
  } else {
    int idx = (b - 4096) * 256 + threadIdx.x;   // t*64 + i
    int t = idx >> 6, i = idx & 63;
    float pos = (float)segpos[t];
    float ts = powf(10000.f, (float)(2 * i) / 128.f);
    float ang = pos / ts;
    tab[idx] = make_float2(sinf(ang), cosf(ang));
  }
}

// ---------------- merged q_w + kv_w transpose: f32 [2048][128] -> bf16 [128][2048] ----------------
__global__ __launch_bounds__(256) void wqkv_transpose_kernel(const float* __restrict__ q_w,
                                                             const float* __restrict__ kv_w,
                                                             unsigned short* __restrict__ Wt) {
  __shared__ float tile[32][33];
  int z = blockIdx.z;   // 0..31: 16 q heads then 16 kv slots
  const float* src = (z < 16) ? q_w + (size_t)z * 2048 * 128
                              : kv_w + (size_t)(z - 16) * 2048 * 128;
  unsigned short* dst = Wt + (size_t)z * 128 * 2048;
  int c0 = blockIdx.x * 32, r0 = blockIdx.y * 32;
  int tx = threadIdx.x & 31, ty = threadIdx.x >> 5;
#pragma unroll
  for (int i = 0; i < 4; ++i)
    tile[ty + i * 8][tx] = src[(size_t)(r0 + ty + i * 8) * 128 + c0 + tx];
  __syncthreads();
#pragma unroll
  for (int i = 0; i < 4; ++i)
    dst[(size_t)(c0 + ty + i * 8) * 2048 + r0 + tx] = f2bf(tile[tx][ty + i * 8]);
}

#define G2L(gp, lp)                                                           \
  __builtin_amdgcn_global_load_lds(                                           \
      (const __attribute__((address_space(1))) void*)(gp),                    \
      (__attribute__((address_space(3))) void*)(lp), 16, 0, 0)
#define GBAR() asm volatile("s_barrier" ::: "memory")
#define VMW(n) asm volatile("s_waitcnt vmcnt(" #n ")" ::: "memory")
#define LG0()  asm volatile("s_waitcnt lgkmcnt(0)" ::: "memory")

// ================= 256x256 8-phase GEMM (QKV): C = A[M][K] * Bt[N][K]^T =================
// (frozen — best-known QKV config, ~68 us / 1010 TF)
template <int OUT_BF16>
__global__ __launch_bounds__(512, 2) void gemm256_kernel(const unsigned short* __restrict__ A,
                                                         const unsigned short* __restrict__ Bt,
                                                         void* __restrict__ Cout,
                                                         int M, int N, int K) {
  extern __shared__ unsigned short smem[];
  unsigned short* ldsA = smem;                      // [2 buf][2 half][8192]
  unsigned short* ldsB = smem + 32768;              // [2 buf][2 half][8192]
  const int tid = threadIdx.x;
  const int lane = tid & 63, wave = tid >> 6;
  const int wm = wave >> 2, wn = wave & 3;
  const int lr = lane & 15, lg = lane >> 4;
  const int swz = (lr & 7) << 3;
  const int c0s = (lg * 8) ^ swz;
  const int c1s = (32 + lg * 8) ^ swz;

  int id = blockIdx.y * gridDim.x + blockIdx.x;
  int nb = gridDim.x * gridDim.y;
  int sw = (id & 7) * (nb >> 3) + (id >> 3);        // bijective, nb % 8 == 0
  const long brow = (long)(sw / gridDim.x) * 256;
  const long bcol = (long)(sw % gridDim.x) * 256;

  const unsigned short* Ag = A + brow * K;
  const unsigned short* Bg = Bt + bcol * K;

  const int r0 = tid >> 3;
  const int cs = ((tid & 7) * 8) ^ ((r0 & 7) << 3);

#define ST_A(tt, b, a)                                                        \
  { G2L(Ag + (size_t)((a) * 128 + r0) * K + (size_t)(tt) * 64 + cs,           \
        ldsA + (b) * 16384 + (a) * 8192 + tid * 8);                           \
    G2L(Ag + (size_t)((a) * 128 + r0 + 64) * K + (size_t)(tt) * 64 + cs,      \
        ldsA + (b) * 16384 + (a) * 8192 + 4096 + tid * 8); }
#define ST_B(tt, b, h)                                                        \
  { G2L(Bg + (size_t)((h) * 128 + r0) * K + (size_t)(tt) * 64 + cs,           \
        ldsB + (b) * 16384 + (h) * 8192 + tid * 8);                           \
    G2L(Bg + (size_t)((h) * 128 + r0 + 64) * K + (size_t)(tt) * 64 + cs,      \
        ldsB + (b) * 16384 + (h) * 8192 + 4096 + tid * 8); }

  f32x4 acc[8][4] = {};
  short8 bf[4][2];
  short8 af[4];

#define RD_B(b)                                                               \
  { const unsigned short* pb = ldsB + (b) * 16384 + wn * 4096;                \
    _Pragma("unroll")                                                         \
    for (int n = 0; n < 4; ++n) {                                             \
      bf[n][0] = *(const short8*)(pb + (n * 16 + lr) * 64 + c0s);             \
      bf[n][1] = *(const short8*)(pb + (n * 16 + lr) * 64 + c1s);             \
    } }
#define RD_A(b, mb)                                                           \
  { const unsigned short* pa = ldsA + (b) * 16384 + wm * 8192;                \
    af[0] = *(const short8*)(pa + ((mb) * 16 + lr) * 64 + c0s);               \
    af[1] = *(const short8*)(pa + ((mb) * 16 + lr) * 64 + c1s);               \
    af[2] = *(const short8*)(pa + ((mb) * 16 + 16 + lr) * 64 + c0s);          \
    af[3] = *(const short8*)(pa + ((mb) * 16 + 16 + lr) * 64 + c1s); }
#define MFMA2(mb)                                                             \
  { __builtin_amdgcn_s_setprio(1);                                            \
    _Pragma("unroll")                                                         \
    for (int n = 0; n < 4; ++n) {                                             \
      acc[mb][n]     = __builtin_amdgcn_mfma_f32_16x16x32_bf16(af[0], bf[n][0], acc[mb][n], 0, 0, 0);     \
      acc[mb][n]     = __builtin_amdgcn_mfma_f32_16x16x32_bf16(af[1], bf[n][1], acc[mb][n], 0, 0, 0);     \
      acc[mb + 1][n] = __builtin_amdgcn_mfma_f32_16x16x32_bf16(af[2], bf[n][0], acc[mb + 1][n], 0, 0, 0); \
      acc[mb + 1][n] = __builtin_amdgcn_mfma_f32_16x16x32_bf16(af[3], bf[n][1], acc[mb + 1][n], 0, 0, 0); \
    }                                                                         \
    __builtin_amdgcn_s_setprio(0); }

  const int NT = K >> 6;
  ST_B(0, 0, 0); ST_B(0, 0, 1); ST_A(0, 0, 0); ST_A(0, 0, 1);
  ST_B(1, 1, 0); ST_B(1, 1, 1);
  VMW(4); GBAR();
  for (int j = 0; j < (NT >> 1); ++j) {
    const int c1 = 2 * j + 1, t2 = 2 * j + 2, t3 = 2 * j + 3;
    const bool s2 = t2 < NT, s3 = t3 < NT;
    RD_B(0); RD_A(0, 0); ST_A(c1, 1, 0);
    GBAR(); LG0(); MFMA2(0); GBAR();
    RD_A(0, 2); ST_A(c1, 1, 1);
    if (s2) ST_B(t2, 0, 0);
    GBAR(); MFMA2(2); GBAR();
    RD_A(0, 4);
    if (s2) ST_B(t2, 0, 1);
    GBAR(); MFMA2(4); GBAR();
    RD_A(0, 6);
    if (s2) { VMW(4); } else { VMW(0); }
    GBAR(); LG0(); MFMA2(6); GBAR();
    RD_B(1); RD_A(1, 0);
    if (s2) ST_A(t2, 0, 0);
    GBAR(); LG0(); MFMA2(0); GBAR();
    RD_A(1, 2);
    if (s2) ST_A(t2, 0, 1);
    if (s3) ST_B(t3, 1, 0);
    GBAR(); MFMA2(2); GBAR();
    RD_A(1, 4);
    if (s3) ST_B(t3, 1, 1);
    GBAR(); MFMA2(4); GBAR();
    RD_A(1, 6);
    if (s3) { VMW(4); } else { VMW(0); }
    GBAR(); LG0(); MFMA2(6); GBAR();
  }

#pragma unroll
  for (int m = 0; m < 8; ++m) {
#pragma unroll
    for (int i = 0; i < 4; ++i) {
      long row = brow + wm * 128 + m * 16 + lg * 4 + i;
#pragma unroll
      for (int n = 0; n < 4; ++n) {
        long col = bcol + wn * 64 + n * 16 + lr;
        if (OUT_BF16)
          ((unsigned short*)Cout)[row * N + col] = f2bf(acc[m][n][i]);
        else
          ((float*)Cout)[row * N + col] = acc[m][n][i];
      }
    }
  }
#undef ST_A
#undef ST_B
#undef RD_A
#undef RD_B
#undef MFMA2
}

// ================= 256x128 O-proj GEMM (BM=256, BN=128), QKV-shape 8-phase =================
// Round-5's NHB=1 config (budgeted ~39-45 us) rebuilt on the race-audited skeleton.
// Per tile: A = 4 G2L (2 ST_A), B = 2 G2L (1 ST_B). Counted vmcnt: VMW(2) at P3/P7
// (leaves next tile's B in flight). LG0 drains at P0/P3/P4/P7 protect same-buffer
// overwrites exactly as in the QKV kernel. grid (16,16) = 256 blocks, LDS 96 KB.
__global__ __launch_bounds__(512, 2) void gemm_ob_kernel(const unsigned short* __restrict__ A,
                                                         const unsigned short* __restrict__ Bt,
                                                         float* __restrict__ Cout,
                                                         int M, int N, int K) {
  extern __shared__ unsigned short smem[];
  unsigned short* ldsA = smem;                      // [2 buf][2 half][8192]  64 KB
  unsigned short* ldsB = smem + 32768;              // [2 buf][8192]          32 KB
  const int tid = threadIdx.x;
  const int lane = tid & 63, wave = tid >> 6;
  const int wm = wave >> 2, wn = wave & 3;
  const int lr = lane & 15, lg = lane >> 4;
  const int swz = (lr & 7) << 3;
  const int c0s = (lg * 8) ^ swz;
  const int c1s = (32 + lg * 8) ^ swz;

  int id = blockIdx.y * gridDim.x + blockIdx.x;
  int nb = gridDim.x * gridDim.y;
  int sw = (id & 7) * (nb >> 3) + (id >> 3);        // bijective, nb % 8 == 0
  const long brow = (long)(sw / gridDim.x) * 256;
  const long bcol = (long)(sw % gridDim.x) * 128;

  const unsigned short* Ag = A + brow * K;
  const unsigned short* Bg = Bt + bcol * K;

  const int r0 = tid >> 3;
  const int cs = ((tid & 7) * 8) ^ ((r0 & 7) << 3);

#define ST_A(tt, b, a)                                                        \
  { G2L(Ag + (size_t)((a) * 128 + r0) * K + (size_t)(tt) * 64 + cs,           \
        ldsA + (b) * 16384 + (a) * 8192 + tid * 8);                           \
    G2L(Ag + (size_t)((a) * 128 + r0 + 64) * K + (size_t)(tt) * 64 + cs,      \
        ldsA + (b) * 16384 + (a) * 8192 + 4096 + tid * 8); }
#define ST_B(tt, b)                                                           \
  { G2L(Bg + (size_t)(r0) * K + (size_t)(tt) * 64 + cs,                       \
        ldsB + (b) * 8192 + tid * 8);                                         \
    G2L(Bg + (size_t)(r0 + 64) * K + (size_t)(tt) * 64 + cs,                  \
        ldsB + (b) * 8192 + 4096 + tid * 8); }

  f32x4 acc[8][2] = {};
  short8 bf[2][2];
  short8 af[4];

#define RD_B(b)                                                               \
  { const unsigned short* pb = ldsB + (b) * 8192 + wn * 2048;                 \
    _Pragma("unroll")                                                         \
    for (int n = 0; n < 2; ++n) {                                             \
      bf[n][0] = *(const short8*)(pb + (n * 16 + lr) * 64 + c0s);             \
      bf[n][1] = *(const short8*)(pb + (n * 16 + lr) * 64 + c1s);             \
    } }
#define RD_A(b, mb)                                                           \
  { const unsigned short* pa = ldsA + (b) * 16384 + wm * 8192;                \
    af[0] = *(const short8*)(pa + ((mb) * 16 + lr) * 64 + c0s);               \
    af[1] = *(const short8*)(pa + ((mb) * 16 + lr) * 64 + c1s);               \
    af[2] = *(const short8*)(pa + ((mb) * 16 + 16 + lr) * 64 + c0s);          \
    af[3] = *(const short8*)(pa + ((mb) * 16 + 16 + lr) * 64 + c1s); }
#define MFMA2(mb)                                                             \
  { __builtin_amdgcn_s_setprio(1);                                            \
    _Pragma("unroll")                                                         \
    for (int n = 0; n < 2; ++n) {                                             \
      acc[mb][n]     = __builtin_amdgcn_mfma_f32_16x16x32_bf16(af[0], bf[n][0], acc[mb][n], 0, 0, 0);     \
      acc[mb][n]     = __builtin_amdgcn_mfma_f32_16x16x32_bf16(af[1], bf[n][1], acc[mb][n], 0, 0, 0);     \
      acc[mb + 1][n] = __builtin_amdgcn_mfma_f32_16x16x32_bf16(af[2], bf[n][0], acc[mb + 1][n], 0, 0, 0); \
      acc[mb + 1][n] = __builtin_amdgcn_mfma_f32_16x16x32_bf16(af[3], bf[n][1], acc[mb + 1][n], 0, 0, 0); \
    }                                                                         \
    __builtin_amdgcn_s_setprio(0); }

  const int NT = K >> 6;
  // prologue: tile0 (B 2 + A 4 = 6 loads) -> buf0, tile1.B (2) -> buf1
  ST_B(0, 0); ST_A(0, 0, 0); ST_A(0, 0, 1);
  ST_B(1, 1);
  VMW(2); GBAR();           // tile0 landed; tile1.B (2) in flight
  for (int j = 0; j < (NT >> 1); ++j) {
    const int c1 = 2 * j + 1, t2 = 2 * j + 2, t3 = 2 * j + 3;
    const bool s2 = t2 < NT, s3 = t3 < NT;
    // P0 (drain: protects buf0.B overwrite at P1)
    RD_B(0); RD_A(0, 0); ST_A(c1, 1, 0);
    GBAR(); LG0(); MFMA2(0); GBAR();
    // P1
    RD_A(0, 2); ST_A(c1, 1, 1);
    if (s2) ST_B(t2, 0);
    GBAR(); MFMA2(2); GBAR();
    // P2
    RD_A(0, 4);
    GBAR(); MFMA2(4); GBAR();
    // P3 (drain + hand-off: tile c1's 6 landed, leave t2.B 2 in flight)
    RD_A(0, 6);
    if (s2) { VMW(2); } else { VMW(0); }
    GBAR(); LG0(); MFMA2(6); GBAR();
    // P4 (drain: protects buf1.B overwrite at P5)
    RD_B(1); RD_A(1, 0);
    if (s2) ST_A(t2, 0, 0);
    GBAR(); LG0(); MFMA2(0); GBAR();
    // P5
    RD_A(1, 2);
    if (s2) ST_A(t2, 0, 1);
    if (s3) ST_B(t3, 1);
    GBAR(); MFMA2(2); GBAR();
    // P6
    RD_A(1, 4);
    GBAR(); MFMA2(4); GBAR();
    // P7 (drain + hand-off: tile t2's 6 landed, leave t3.B 2 in flight)
    RD_A(1, 6);
    if (s3) { VMW(2); } else { VMW(0); }
    GBAR(); LG0(); MFMA2(6); GBAR();
  }

#pragma unroll
  for (int m = 0; m < 8; ++m) {
#pragma unroll
    for (int i = 0; i < 4; ++i) {
      long row = brow + wm * 128 + m * 16 + lg * 4 + i;
#pragma unroll
      for (int n = 0; n < 2; ++n) {
        long col = bcol + wn * 32 + n * 16 + lr;
        Cout[row * N + col] = acc[m][n][i];
      }
    }
  }
#undef ST_A
#undef ST_B
#undef RD_A
#undef RD_B
#undef MFMA2
}

// ---------------- merged RoPE apply + V transpose + o_w transpose ----------------
__global__ __launch_bounds__(256) void rope_vt_ow_kernel(const unsigned short* __restrict__ raw,
                                                         const float2* __restrict__ tab,
                                                         unsigned short* __restrict__ Qb,
                                                         unsigned short* __restrict__ Kb,
                                                         unsigned short* __restrict__ Vt,
                                                         const float* __restrict__ o_w,
                                                         unsigned short* __restrict__ o_wt) {
  __shared__ unsigned short tileU[32][33];
  __shared__ float tileF[32][33];
  int b = blockIdx.x;
  if (b < 3072) {
    int gid = b * 256 + threadIdx.x;
    int j = gid & 7;
    int rem = gid >> 3;
    int hs = rem % 24;
    int t = rem / 24;
    int i0 = j * 8;
    float sv[8], cv[8];
    const float2* tp = tab + t * 64 + i0;
#pragma unroll
    for (int q = 0; q < 8; ++q) { float2 sc2 = tp[q]; sv[q] = sc2.x; cv[q] = sc2.y; }
    if (hs < 16) {
      const unsigned short* p = raw + (size_t)t * 4096 + hs * 128 + i0;
      ushort8 a = *(const ushort8*)p;
      ushort8 c = *(const ushort8*)(p + 64);
      ushort8 o1, o2;
#pragma unroll
      for (int q = 0; q < 8; ++q) {
        float fa = bf2f(a[q]), fb = bf2f(c[q]);
        o1[q] = f2bf((fa * cv[q] - fb * sv[q]) * QSCALE);
        o2[q] = f2bf((fb * cv[q] + fa * sv[q]) * QSCALE);
      }
      unsigned short* qp = Qb + ((size_t)hs * T_SEQ + t) * 128 + i0;
      *(ushort8*)qp = o1;
      *(ushort8*)(qp + 64) = o2;
    } else {
      int kn = hs - 16;
      const unsigned short* p = raw + (size_t)t * 4096 + 2048 + kn * 128 + i0;
      ushort8 a = *(const ushort8*)p;
      ushort8 c = *(const ushort8*)(p + 64);
      ushort8 o1, o2;
#pragma unroll
      for (int q = 0; q < 8; ++q) {
        float fa = bf2f(a[q]), fb = bf2f(c[q]);
        o1[q] = f2bf(fa * cv[q] - fb * sv[q]);
        o2[q] = f2bf(fb * cv[q] + fa * sv[q]);
      }
      unsigned short* kp = Kb + ((size_t)kn * T_SEQ + t) * 128 + i0;
      *(ushort8*)kp = o1;
      *(ushort8*)(kp + 64) = o2;
    }
  } else if (b < 7168) {
    int id = b - 3072;                 // 0..4095: V transpose
    int bx = id & 3, by = (id >> 2) & 127, bz = id >> 9;
    const unsigned short* src = raw + 3072 + (size_t)bz * 128;
    unsigned short* dst = Vt + (size_t)bz * 128 * 4096;
    int c0 = bx * 32, r0 = by * 32;
    int tx = threadIdx.x & 31, ty = threadIdx.x >> 5;
#pragma unroll
    for (int i = 0; i < 4; ++i)
      tileU[ty + i * 8][tx] = src[(size_t)(r0 + ty + i * 8) * 4096 + c0 + tx];
    __syncthreads();
#pragma unroll
    for (int i = 0; i < 4; ++i)
      dst[(size_t)(c0 + ty + i * 8) * 4096 + r0 + tx] = tileU[tx][ty + i * 8];
  } else {
    int id = b - 7168;                 // 0..4095: o_w transpose f32 -> bf16^T
    int bx = id & 63, by = id >> 6;
    int c0 = bx * 32, r0 = by * 32;
    int tx = threadIdx.x & 31, ty = threadIdx.x >> 5;
#pragma unroll
    for (int i = 0; i < 4; ++i)
      tileF[ty + i * 8][tx] = o_w[(size_t)(r0 + ty + i * 8) * 2048 + c0 + tx];
    __syncthreads();
#pragma unroll
    for (int i = 0; i < 4; ++i)
      o_wt[(size_t)(c0 + ty + i * 8) * 2048 + r0 + tx] = f2bf(tileF[tx][ty + i * 8]);
  }
}

// ---------------- Flash attention: sliding window + tanh soft-cap ----------------
__global__ __launch_bounds__(512, 2) void attn_kernel(const unsigned short* __restrict__ Qb,
                                                      const unsigned short* __restrict__ Kb,
                                                      const unsigned short* __restrict__ Vt,
                                                      unsigned short* __restrict__ enc) {
  __shared__ unsigned short Ks[2][64][128];  // [buf][key][d], global col pre-swizzled
  __shared__ unsigned short Vs[2][128][64];  // [buf][d][key]
  __shared__ unsigned short Ps[8][32][72];   // [wave][q][key]
  int rawb = blockIdx.x;                     // 256 blocks
  int lin = (rawb & 7) * 32 + (rawb >> 3);   // bijective; 32/XCD = 2 heads = 1 kv head
  const int h = lin >> 4;
  const int qb0 = (lin & 15) * 256;
  const int kvh = h >> 1;
  const int tid = threadIdx.x, lane = tid & 63, wave = tid >> 6;
  const int qw = qb0 + wave * 32;
  const int lr = lane & 15, lg = lane >> 4;
  const int sw = (lr & 7) << 3;
  const int ck0 = (lg * 8) ^ sw, ck1 = (32 + lg * 8) ^ sw;
  const int ck2 = (64 + lg * 8) ^ sw, ck3 = (96 + lg * 8) ^ sw;

  short8 aq[2][4];
#pragma unroll
  for (int g = 0; g < 2; ++g) {
    const unsigned short* qp = Qb + ((size_t)h * T_SEQ + qw + g * 16 + lr) * 128 + lg * 8;
#pragma unroll
    for (int c = 0; c < 4; ++c) aq[g][c] = *(const short8*)(qp + c * 32);
  }
  f32x4 acc[2][8] = {};
  float lsum[2] = {0.f, 0.f};

  const int s_lo = (qb0 - 1023) > 0 ? (qb0 - 1023) : 0;
  const int kb_lo = s_lo >> 6, kb_hi = (qb0 + 255) >> 6;

  const int rK = tid >> 4;                 // 0..31: K rows rK, rK+32
  const int cpK = (tid & 15) * 8;
  const int colK = cpK ^ ((rK & 7) << 3);
  const int rV = tid >> 3;                 // 0..63: V rows rV, rV+64
  const int cpV = (tid & 7) * 8;
  const int colV = cpV ^ ((rV & 7) << 3);
  const unsigned short* kgb = Kb + ((size_t)kvh * T_SEQ + rK) * 128 + colK;
  const unsigned short* vgb = Vt + ((size_t)kvh * 128 + rV) * T_SEQ + colV;

  ushort8 kr0, kr1, vr0, vr1;
  {
    const int s0g = kb_lo * 64;
    kr0 = *(const ushort8*)(kgb + (size_t)s0g * 128);
    kr1 = *(const ushort8*)(kgb + (size_t)(s0g + 32) * 128);
    vr0 = *(const ushort8*)(vgb + s0g);
    vr1 = *(const ushort8*)(vgb + (size_t)64 * T_SEQ + s0g);
  }

  const int qg0 = qw + lr, qg1 = qw + 16 + lr;
  for (int kb = kb_lo; kb <= kb_hi; ++kb) {
    const int s0g = kb * 64;
    const int buf = kb & 1;
    *(ushort8*)&Ks[buf][rK][cpK] = kr0;
    *(ushort8*)&Ks[buf][rK + 32][cpK] = kr1;
    *(ushort8*)&Vs[buf][rV][cpV] = vr0;
    *(ushort8*)&Vs[buf][rV + 64][cpV] = vr1;
    __syncthreads();
    if (kb < kb_hi) {
      const int sn = s0g + 64;
      kr0 = *(const ushort8*)(kgb + (size_t)sn * 128);
      kr1 = *(const ushort8*)(kgb + (size_t)(sn + 32) * 128);
      vr0 = *(const ushort8*)(vgb + sn);
      vr1 = *(const ushort8*)(vgb + (size_t)64 * T_SEQ + sn);
    }
    if (s0g > qw + 31 || s0g + 63 < qw - 1023) continue;
    const bool interior = (s0g + 63 <= qw) && (s0g >= qw - 992);

    f32x4 sT0[4] = {}, sT1[4] = {};
    __builtin_amdgcn_s_setprio(1);
#pragma unroll
    for (int st = 0; st < 4; ++st) {
      const unsigned short* kp = &Ks[buf][st * 16 + lr][0];
      short8 k0 = *(const short8*)(kp + ck0);
      short8 k1 = *(const short8*)(kp + ck1);
      short8 k2 = *(const short8*)(kp + ck2);
      short8 k3 = *(const short8*)(kp + ck3);
      sT0[st] = __builtin_amdgcn_mfma_f32_16x16x32_bf16(k0, aq[0][0], sT0[st], 0, 0, 0);
      sT1[st] = __builtin_amdgcn_mfma_f32_16x16x32_bf16(k0, aq[1][0], sT1[st], 0, 0, 0);
      sT0[st] = __builtin_amdgcn_mfma_f32_16x16x32_bf16(k1, aq[0][1], sT0[st], 0, 0, 0);
      sT1[st] = __builtin_amdgcn_mfma_f32_16x16x32_bf16(k1, aq[1][1], sT1[st], 0, 0, 0);
      sT0[st] = __builtin_amdgcn_mfma_f32_16x16x32_bf16(k2, aq[0][2], sT0[st], 0, 0, 0);
      sT1[st] = __builtin_amdgcn_mfma_f32_16x16x32_bf16(k2, aq[1][2], sT1[st], 0, 0, 0);
      sT0[st] = __builtin_amdgcn_mfma_f32_16x16x32_bf16(k3, aq[0][3], sT0[st], 0, 0, 0);
      sT1[st] = __builtin_amdgcn_mfma_f32_16x16x32_bf16(k3, aq[1][3], sT1[st], 0, 0, 0);
    }
    __builtin_amdgcn_s_setprio(0);

#pragma unroll
    for (int g = 0; g < 2; ++g) {
      const f32x4* sTg = g ? sT1 : sT0;
      const int qgg = g ? qg1 : qg0;
#pragma unroll
      for (int st = 0; st < 4; ++st) {
        f32x4 svv = sTg[st];
        f32x2 sa, sb;
        sa[0] = svv[0]; sa[1] = svv[1]; sb[0] = svv[2]; sb[1] = svv[3];
        f32x2 ua = sa * sa, ub = sb * sb;
        f32x2 numa = ua * 4.0e-4f + 15.f, numb = ub * 4.0e-4f + 15.f;
        f32x2 dena = ua * 2.4e-3f + 15.f, denb = ub * 2.4e-3f + 15.f;
        f32x2 ra, rb;
        ra[0] = __builtin_amdgcn_rcpf(dena[0]); ra[1] = __builtin_amdgcn_rcpf(dena[1]);
        rb[0] = __builtin_amdgcn_rcpf(denb[0]); rb[1] = __builtin_amdgcn_rcpf(denb[1]);
        f32x2 ea = (sa * 1.44269504f) * numa * ra;
        f32x2 eb = (sb * 1.44269504f) * numb * rb;
        float e[4] = {ea[0], ea[1], eb[0], eb[1]};
        float p[4];
#pragma unroll
        for (int r = 0; r < 4; ++r) {
          if (!interior) {
            int sg = s0g + st * 16 + lg * 4 + r;
            e[r] = ((unsigned)(qgg - sg) <= 1023u) ? e[r] : -__builtin_inff();
          }
          asm("v_exp_f32 %0, %1" : "=v"(p[r]) : "v"(e[r]));
        }
        lsum[g] += (p[0] + p[1]) + (p[2] + p[3]);
        unsigned u0, u1;
        asm("v_cvt_pk_bf16_f32 %0, %1, %2" : "=v"(u0) : "v"(p[0]), "v"(p[1]));
        asm("v_cvt_pk_bf16_f32 %0, %1, %2" : "=v"(u1) : "v"(p[2]), "v"(p[3]));
        uint2 w; w.x = u0; w.y = u1;
        *(uint2*)&Ps[wave][g * 16 + lr][st * 16 + lg * 4] = w;
      }
    }
    short8 pa00 = *(const short8*)&Ps[wave][lr][lg * 8];
    short8 pa01 = *(const short8*)&Ps[wave][lr][32 + lg * 8];
    short8 pa10 = *(const short8*)&Ps[wave][16 + lr][lg * 8];
    short8 pa11 = *(const short8*)&Ps[wave][16 + lr][32 + lg * 8];
    __builtin_amdgcn_s_setprio(1);
#pragma unroll
    for (int d0 = 0; d0 < 8; ++d0) {
      const unsigned short* vp = &Vs[buf][d0 * 16 + lr][0];
      short8 bv0 = *(const short8*)(vp + ((lg * 8) ^ sw));
      short8 bv1 = *(const short8*)(vp + ((32 + lg * 8) ^ sw));
      acc[0][d0] = __builtin_amdgcn_mfma_f32_16x16x32_bf16(pa00, bv0, acc[0][d0], 0, 0, 0);
      acc[1][d0] = __builtin_amdgcn_mfma_f32_16x16x32_bf16(pa10, bv0, acc[1][d0], 0, 0, 0);
      acc[0][d0] = __builtin_amdgcn_mfma_f32_16x16x32_bf16(pa01, bv1, acc[0][d0], 0, 0, 0);
      acc[1][d0] = __builtin_amdgcn_mfma_f32_16x16x32_bf16(pa11, bv1, acc[1][d0], 0, 0, 0);
    }
    __builtin_amdgcn_s_setprio(0);
  }

#pragma unroll
  for (int g = 0; g < 2; ++g) {
    float l = lsum[g];
    l += __shfl_xor(l, 16);
    l += __shfl_xor(l, 32);
#pragma unroll
    for (int r = 0; r < 4; ++r) {
      float lt = __shfl(l, lg * 4 + r);
      float inv = __builtin_amdgcn_rcpf(lt);
      int row = qw + g * 16 + lg * 4 + r;
      unsigned short* op = enc + (size_t)row * D_MODEL + h * 128 + lr;
#pragma unroll
      for (int d0 = 0; d0 < 8; ++d0) op[d0 * 16] = f2bf(acc[g][d0][r] * inv);
    }
  }
}

// ---------------- launch ----------------
extern "C" void kernel_launch(void* const* d_in, const int* in_sizes, int n_in,
                              void* d_out, int out_size, void* d_ws, size_t ws_size,
                              hipStream_t stream) {
  const float* x = (const float*)d_in[0];
  const int* segpos = (const int*)d_in[1];
  // d_in[2]: attn_mask (pure causal tril) — computed analytically, not read
  const float* q_w = (const float*)d_in[3];
  const float* kv_w = (const float*)d_in[4];
  const float* o_w = (const float*)d_in[5];
  float* out = (float*)d_out;
  char* ws = (char*)d_ws;

  const size_t OFF_XB = 0;                       // 16.8 MB  x bf16 [4096][2048]
  const size_t OFF_WT = OFF_XB + 16777216;       // 16.8 MB  Wqkv^T bf16 [4096][2048]
  const size_t OFF_RAW = OFF_WT + 16777216;      // 33.6 MB  qkv raw bf16 [4096][4096]
  const size_t OFF_KB = OFF_RAW + 33554432;      // 8.4 MB   K roped [8][4096][128]
  const size_t OFF_VT = OFF_KB + 8388608;        // 8.4 MB   V^T [8][128][4096]
  const size_t OFF_TAB = OFF_VT + 8388608;       // 2 MB     rope table
  unsigned short* xb = (unsigned short*)(ws + OFF_XB);
  unsigned short* Wt = (unsigned short*)(ws + OFF_WT);
  unsigned short* raw = (unsigned short*)(ws + OFF_RAW);
  unsigned short* Kb = (unsigned short*)(ws + OFF_KB);
  unsigned short* Vt = (unsigned short*)(ws + OFF_VT);
  float2* tab = (float2*)(ws + OFF_TAB);
  unsigned short* o_wt = xb;   // alias: built after qkv GEMM consumed xb
  unsigned short* Qb = Wt;     // alias: built after qkv GEMM consumed Wt
  unsigned short* enc = raw;   // alias: written after V transpose consumed raw

  hipFuncSetAttribute((const void*)(gemm256_kernel<1>),
                      hipFuncAttributeMaxDynamicSharedMemorySize, 131072);
  hipFuncSetAttribute((const void*)gemm_ob_kernel,
                      hipFuncAttributeMaxDynamicSharedMemorySize, 98304);

  prep_kernel<<<dim3(5120), dim3(256), 0, stream>>>(x, xb, segpos, tab);
  wqkv_transpose_kernel<<<dim3(4, 64, 32), dim3(256), 0, stream>>>(q_w, kv_w, Wt);
  // qkv projection: 256x256 tile, 256 blocks
  gemm256_kernel<1><<<dim3(16, 16), dim3(512), 131072, stream>>>(xb, Wt, (void*)raw, 4096, 4096, 2048);
  // rope (3072) + V transpose (4096) + o_w transpose (4096)
  rope_vt_ow_kernel<<<dim3(11264), dim3(256), 0, stream>>>(raw, tab, Qb, Kb, Vt, o_w, o_wt);
  attn_kernel<<<dim3(256), dim3(512), 0, stream>>>(Qb, Kb, Vt, enc);
  // output projection: 256x128 tile (BM=256), grid (16,16) = 256 blocks
  gemm_ob_kernel<<<dim3(16, 16), dim3(512), 98304, stream>>>(enc, o_wt, out, 4096, 2048, 2048);
}